// Round 12
// baseline (148.407 us; speedup 1.0000x reference)
//
#include <hip/hip_runtime.h>
#include <stdint.h>
#include <math.h>

// Problem constants
#define NV 32      // num_vari (groups)
#define NB 4096    // batch
#define NK 256     // 2*dim_per_vari (contraction)
#define NO 256     // dim_to (output features)

#define TROWS 16   // rows per tile (one MFMA M)
#define NTILE 8    // tiles per block (slab = 128 rows)

typedef __bf16 bf16x8 __attribute__((ext_vector_type(8)));
typedef float  f32x4  __attribute__((ext_vector_type(4)));

__device__ __forceinline__ f32x4 mfma16(bf16x8 a, bf16x8 b, f32x4 c) {
    return __builtin_amdgcn_mfma_f32_16x16x32_bf16(a, b, c, 0, 0, 0);
}

__device__ __forceinline__ float softplus_f(float z) {
    return fmaxf(z, 0.0f) + __logf(1.0f + __expf(-fabsf(z)));
}

// volatile-asm 16B loads: issued in program order, cannot be rematerialized,
// sunk, or serialized by LLVM -- the wave keeps all of them in flight.
// NOTE: results are NOT tracked by the compiler's waitcnt insertion; an
// explicit s_waitcnt + sched_barrier(0) must precede first use (rule #18).
__device__ __forceinline__ bf16x8 pin_load_b16x8(const __bf16* p) {
    bf16x8 r;
    asm volatile("global_load_dwordx4 %0, %1, off" : "=v"(r) : "v"(p) : "memory");
    return r;
}
__device__ __forceinline__ f32x4 pin_load_f32x4(const float* p) {
    f32x4 r;
    asm volatile("global_load_dwordx4 %0, %1, off" : "=v"(r) : "v"(p) : "memory");
    return r;
}

// ---------------------------------------------------------------------------
// prep: W[v][k][o] fp32  ->  Wt[v][o][k] bf16  (transpose + convert, 4 MB)
__global__ __launch_bounds__(256)
void prep_wt_kernel(const float* __restrict__ w, __bf16* __restrict__ wt) {
    const int id = blockIdx.x * 256 + threadIdx.x;   // 262144
    const int o  = id & 255;
    const int kc = (id >> 8) & 31;
    const int v  = id >> 13;
    const float* src = w + ((size_t)v * NK + (size_t)kc * 8) * NO + o;
    bf16x8 r;
#pragma unroll
    for (int j = 0; j < 8; ++j) r[j] = (__bf16)src[(size_t)j * NO];
    *(bf16x8*)(wt + ((size_t)v * NO + o) * NK + kc * 8) = r;
}

// ---------------------------------------------------------------------------
// main: out[v][b][o] = softplus( x[v][b][:] . Wt[v][o][:] + 256*bias[v][o] )
//
// Copy-kernel shape: NO LDS, NO barriers, NO cross-wave deps. W pinned in
// regs (volatile-asm). Per 16-row tile: 16 volatile-asm x loads back-to-back
// (16 KB in flight/wave), ONE vmcnt(0)+sched_barrier, cvt, 16 MFMA, softplus,
// 2 stores. 12 waves/CU drift freely -> HBM stream self-smooths.
__global__ __launch_bounds__(256, 3)
void mv_dense_kernel(const float* __restrict__ x, const __bf16* __restrict__ wt,
                     const float* __restrict__ bias, float* __restrict__ out) {
    const int t    = threadIdx.x;
    const int w    = t >> 6;      // wave 0..3 -> o-columns [obase, obase+32)
    const int lane = t & 63;
    const int lr   = lane & 15;   // fragment row (batch) / W row (o)
    const int lg   = lane >> 4;   // k-group (8 contiguous k)

    // XCD-chunked: 2048 blocks = 8 XCD x 256. lb = v(5b)|slab(5b)|oh(1b):
    // each XCD owns 4 whole v's (Wt 512 KB/L2); oh-pairs adjacent -> same
    // XCD reads the same x slab (L2 absorbs the 2x re-read).
    const int bid  = blockIdx.x;
    const int lb   = (bid & 7) * 256 + (bid >> 3);
    const int v    = lb >> 6;            // 0..31
    const int slab = (lb & 63) >> 1;     // 0..31 -> 128 rows each
    const int oh   = lb & 1;             // o-half

    const int obase = oh * 128 + w * 32;

    const float* xg = x   + ((size_t)v * NB + (size_t)slab * 128) * NK;
    float*       og = out + ((size_t)v * NB + (size_t)slab * 128) * NO;

    // ---- pin W fragments (16 x bf16x8 = 64 regs, loaded once, L2-hot) ----
    const __bf16* wp0 = wt + ((size_t)v * NO + obase + lr) * NK + lg * 8;
    const __bf16* wp1 = wp0 + (size_t)16 * NK;
    bf16x8 wv0[8], wv1[8];
#pragma unroll
    for (int kk = 0; kk < 8; ++kk) {
        wv0[kk] = pin_load_b16x8(wp0 + kk * 32);
        wv1[kk] = pin_load_b16x8(wp1 + kk * 32);
    }

    // bias, pre-scaled by 256, per C-fragment layout (o = obase + j*16 + lg*4 + r)
    const float* bg = bias + (size_t)v * NO + obase + lg * 4;
    f32x4 bb0 = *(const f32x4*)bg;
    f32x4 bb1 = *(const f32x4*)(bg + 16);

    asm volatile("s_waitcnt vmcnt(0)" ::: "memory");
    __builtin_amdgcn_sched_barrier(0);
#pragma unroll
    for (int r = 0; r < 4; ++r) { bb0[r] *= 256.0f; bb1[r] *= 256.0f; }

    // per-lane x source / out dest (row lr of each tile)
    const float* xp = xg + (size_t)lr * NK + lg * 8;
    float*       op = og + (size_t)lr * NO + obase + lg * 4;

#pragma unroll 1
    for (int tt = 0; tt < NTILE; ++tt) {
        const float* xi = xp + (size_t)tt * TROWS * NK;

        // ---- issue all 16 x loads back-to-back (16 KB in flight) ----
        f32x4 lo[8], hi[8];
#pragma unroll
        for (int kk = 0; kk < 8; ++kk) {
            lo[kk] = pin_load_f32x4(xi + kk * 32);
            hi[kk] = pin_load_f32x4(xi + kk * 32 + 4);
        }
        asm volatile("s_waitcnt vmcnt(0)" ::: "memory");
        __builtin_amdgcn_sched_barrier(0);

        // ---- cvt + MFMA (W from pinned regs only) ----
        f32x4 acc0 = {0.f, 0.f, 0.f, 0.f};
        f32x4 acc1 = {0.f, 0.f, 0.f, 0.f};
#pragma unroll
        for (int kk = 0; kk < 8; ++kk) {
            bf16x8 a;
#pragma unroll
            for (int e = 0; e < 4; ++e) { a[e] = (__bf16)lo[kk][e]; a[e + 4] = (__bf16)hi[kk][e]; }
            acc0 = mfma16(wv0[kk], a, acc0);
            acc1 = mfma16(wv1[kk], a, acc1);
        }

        // ---- epilogue: batch = slab*128 + tt*16 + lr, o = obase + {0,16} + lg*4 + r
        float* o = op + (size_t)tt * TROWS * NO;
        f32x4 r0, r1;
#pragma unroll
        for (int r = 0; r < 4; ++r) {
            r0[r] = softplus_f(acc0[r] + bb0[r]);
            r1[r] = softplus_f(acc1[r] + bb1[r]);
        }
        *(f32x4*)o        = r0;
        *(f32x4*)(o + 16) = r1;
    }
}

extern "C" void kernel_launch(void* const* d_in, const int* in_sizes, int n_in,
                              void* d_out, int out_size, void* d_ws, size_t ws_size,
                              hipStream_t stream) {
    const float* x  = (const float*)d_in[0];
    const float* w  = (const float*)d_in[1];
    const float* b  = (const float*)d_in[2];
    float* out      = (float*)d_out;
    __bf16* wt      = (__bf16*)d_ws;   // 4 MB scratch

    hipLaunchKernelGGL(prep_wt_kernel, dim3(1024), dim3(256), 0, stream, w, wt);
    // 2048 blocks x 256 thr (4 waves); no LDS -> 3 blocks/CU (VGPR-capped)
    hipLaunchKernelGGL(mv_dense_kernel, dim3(2048), dim3(256), 0, stream,
                       x, wt, b, out);
}

// Round 13
// 67.418 us; speedup vs baseline: 2.2013x; 2.2013x over previous
//
#include <hip/hip_runtime.h>
#include <stdint.h>
#include <math.h>

// Problem constants
#define NV 32      // num_vari (groups)
#define NB 4096    // batch
#define NK 256     // 2*dim_per_vari (contraction)
#define NO 256     // dim_to (output features)

#define TROWS 16   // rows per m-tile
#define NTILE 16   // m-tiles per block (slab = 256 rows)

typedef __bf16 bf16x8 __attribute__((ext_vector_type(8)));
typedef float  f32x4  __attribute__((ext_vector_type(4)));

__device__ __forceinline__ f32x4 mfma16(bf16x8 a, bf16x8 b, f32x4 c) {
    return __builtin_amdgcn_mfma_f32_16x16x32_bf16(a, b, c, 0, 0, 0);
}

__device__ __forceinline__ float softplus_f(float z) {
    return fmaxf(z, 0.0f) + __logf(1.0f + __expf(-fabsf(z)));
}

__device__ __forceinline__ void gload_lds16(const void* g, void* l) {
    // async global->LDS DMA, 16 B/lane; LDS dest = wave-uniform base + lane*16
    __builtin_amdgcn_global_load_lds((const __attribute__((address_space(1))) uint32_t*)g,
                                     (__attribute__((address_space(3))) uint32_t*)l,
                                     16, 0, 0);
}

// volatile-asm 16B load: cannot be rematerialized/sunk -> dest regs stay live
// across the whole tile loop (W-pinning trick, validated r11/r12).
__device__ __forceinline__ bf16x8 pin_load16(const __bf16* p) {
    bf16x8 r;
    asm volatile("global_load_dwordx4 %0, %1, off" : "=v"(r) : "v"(p) : "memory");
    return r;
}

// ---------------------------------------------------------------------------
// prep: W[v][k][o] fp32  ->  Wt[v][o][k] bf16  (transpose + convert, 4 MB)
__global__ __launch_bounds__(256)
void prep_wt_kernel(const float* __restrict__ w, __bf16* __restrict__ wt) {
    const int id = blockIdx.x * 256 + threadIdx.x;   // 262144
    const int o  = id & 255;
    const int kc = (id >> 8) & 31;
    const int v  = id >> 13;
    const float* src = w + ((size_t)v * NK + (size_t)kc * 8) * NO + o;
    bf16x8 r;
#pragma unroll
    for (int j = 0; j < 8; ++j) r[j] = (__bf16)src[(size_t)j * NO];
    *(bf16x8*)(wt + ((size_t)v * NO + o) * NK + kc * 8) = r;
}

// ---------------------------------------------------------------------------
// main: out[v][b][o] = softplus( x[v][b][:] . Wt[v][o][:] + 256*bias[v][o] )
//
// 4 waves/block, 64 o-cols per wave: W pinned = 32 bf16x8 = 128 VGPR.
// Each x fragment-read feeds 4 MFMAs (LDS amplification halved vs r11).
// x: 16-row fp32 tiles via global_load_lds DMA, triple buffer, stage-ahead-2,
// vmcnt(8)+barrier fence at iteration top, 4-bit XOR slot swizzle.
__global__ __launch_bounds__(256, 2)
void mv_dense_kernel(const float* __restrict__ x, const __bf16* __restrict__ wt,
                     const float* __restrict__ bias, float* __restrict__ out) {
    __shared__ float Xs[3][TROWS * NK];   // 3 x 16 KB

    const int t    = threadIdx.x;
    const int w    = t >> 6;      // wave 0..3 -> o-columns [w*64, w*64+64)
    const int lane = t & 63;
    const int lr   = lane & 15;
    const int lg   = lane >> 4;

    // XCD-chunked: 512 blocks = 8 XCD x 64; each XCD owns 4 v's (Wt 512KB/L2)
    const int bid  = blockIdx.x;
    const int lb   = (bid & 7) * 64 + (bid >> 3);
    const int v    = lb >> 4;     // 0..31
    const int slab = lb & 15;     // 256 rows each

    const float* xg = x   + ((size_t)v * NB + (size_t)slab * 256) * NK;
    float*       og = out + ((size_t)v * NB + (size_t)slab * 256) * NO;

    // ---- pin W fragments: 4 o-tiles x 8 kk = 32 x bf16x8 = 128 regs ----
    bf16x8 wv[4][8];
#pragma unroll
    for (int j = 0; j < 4; ++j) {
        const __bf16* wp = wt + ((size_t)v * NO + w * 64 + j * 16 + lr) * NK + lg * 8;
#pragma unroll
        for (int kk = 0; kk < 8; ++kk)
            wv[j][kk] = pin_load16(wp + kk * 32);
    }

    // bias, pre-scaled by 256, per C-fragment layout (o = w*64 + j*16 + lg*4 + r)
    f32x4 bb[4];
#pragma unroll
    for (int j = 0; j < 4; ++j)
        bb[j] = *(const f32x4*)(bias + (size_t)v * NO + w * 64 + j * 16 + lg * 4);

    // ---- DMA staging: 4 gload_lds/thread; wave w fills rows {w,w+4,w+8,w+12}
    // LDS phys slot = lane (linear dest); global logical slot = lane ^ (r&15)
    auto stage = [&](int tile, int buf) {
        const float* tsrc = xg + (size_t)tile * TROWS * NK;
        char* lbase = (char*)&Xs[buf][0];
#pragma unroll
        for (int d = 0; d < 4; ++d) {
            const int r = d * 4 + w;                    // r & 15 == r
            gload_lds16(tsrc + (size_t)r * NK + (lane ^ r) * 4,
                        (void*)(lbase + (size_t)r * 1024));
        }
    };

    // compute one 16-row tile; W from pinned registers only
    auto compute = [&](int tt, const char* tb) {
        f32x4 acc[4];
#pragma unroll
        for (int j = 0; j < 4; ++j) {
            f32x4 z4 = {0.f, 0.f, 0.f, 0.f};
            acc[j] = z4;
        }
#pragma unroll
        for (int kk = 0; kk < 8; ++kk) {
            // row = lr, logical slots {kk*8+lg*2, +1}, phys = ^ lr (4-bit XOR)
            const int phys = (kk * 8 + lg * 2) ^ lr;
            const char* rb = tb + (size_t)lr * 1024;
            f32x4 lo = *(const f32x4*)(rb + phys * 16);
            f32x4 hi = *(const f32x4*)(rb + (phys ^ 1) * 16);
            bf16x8 a;
#pragma unroll
            for (int e = 0; e < 4; ++e) { a[e] = (__bf16)lo[e]; a[e + 4] = (__bf16)hi[e]; }
#pragma unroll
            for (int j = 0; j < 4; ++j)
                acc[j] = mfma16(wv[j][kk], a, acc[j]);
        }
        // epilogue: batch = tt*16 + lr, o = w*64 + j*16 + lg*4 + r
        float* op = og + (size_t)(tt * TROWS + lr) * NO + w * 64 + lg * 4;
#pragma unroll
        for (int j = 0; j < 4; ++j) {
            f32x4 res;
#pragma unroll
            for (int r = 0; r < 4; ++r)
                res[r] = softplus_f(acc[j][r] + 256.0f * bb[j][r]);
            *(f32x4*)(op + j * 16) = res;
        }
    };

    // ---- pipeline prologue: W pins + bias + 2 tiles drained once ----
    stage(0, 0);
    stage(1, 1);
    asm volatile("s_waitcnt vmcnt(0)" ::: "memory");
    __builtin_amdgcn_s_barrier();
    __builtin_amdgcn_sched_barrier(0);
    stage(2, 2);
    compute(0, (const char*)&Xs[0][0]);

    // steady state: per iter [4 DMA][4 stores]; at the fence the 8 youngest
    // VMEM ops are 4 DMA(tt+1) + 4 stores(tt-1) -> vmcnt(8) guarantees tile
    // tt's DMAs landed. ONE 4-wave barrier per tile; zero W traffic.
#pragma unroll 1
    for (int tt = 1; tt < NTILE; ++tt) {
        asm volatile("s_waitcnt vmcnt(8)" ::: "memory");
        __builtin_amdgcn_s_barrier();
        __builtin_amdgcn_sched_barrier(0);
        if (tt + 2 < NTILE) stage(tt + 2, (tt + 2) % 3);   // buf of tt-1 (reads done)
        compute(tt, (const char*)&Xs[tt % 3][0]);
    }
}

extern "C" void kernel_launch(void* const* d_in, const int* in_sizes, int n_in,
                              void* d_out, int out_size, void* d_ws, size_t ws_size,
                              hipStream_t stream) {
    const float* x  = (const float*)d_in[0];
    const float* w  = (const float*)d_in[1];
    const float* b  = (const float*)d_in[2];
    float* out      = (float*)d_out;
    __bf16* wt      = (__bf16*)d_ws;   // 4 MB scratch

    hipLaunchKernelGGL(prep_wt_kernel, dim3(1024), dim3(256), 0, stream, w, wt);
    // 512 blocks x 256 thr (4 waves); 2 blocks/CU (VGPR-capped at 2 waves/SIMD)
    hipLaunchKernelGGL(mv_dense_kernel, dim3(512), dim3(256), 0, stream,
                       x, wt, b, out);
}